// Round 3
// baseline (522.568 us; speedup 1.0000x reference)
//
#include <hip/hip_runtime.h>
#include <hip/hip_bf16.h>

#define S_LEN 50
#define BATCH 128
#define DIM 256
#define NITEMS 50001
#define NPAD 50048
#define GDIM 768
#define NSEQ 6400  // S_LEN*BATCH

typedef __attribute__((ext_vector_type(8))) short short8;
typedef __attribute__((ext_vector_type(4))) short short4_;
typedef __attribute__((ext_vector_type(4))) float float4_;

static __device__ __forceinline__ unsigned short f2bf(float x){
  union { float f; unsigned u; } v; v.f = x;
  unsigned r = v.u + 0x7FFFu + ((v.u >> 16) & 1u);
  return (unsigned short)(r >> 16);
}
static __device__ __forceinline__ float bf2f(unsigned short h){
  union { unsigned u; float f; } v; v.u = ((unsigned)h) << 16;
  return v.f;
}
static __device__ __forceinline__ float sigm(float x){ return 1.f/(1.f + __expf(-x)); }

// ---------------- kernel 1: convert W_ih / W_hh to bf16 ----------------
__global__ void k_conv_w(const float* __restrict__ a, const float* __restrict__ b,
                         unsigned short* __restrict__ oa, unsigned short* __restrict__ ob, int n4){
  int i = blockIdx.x*256 + threadIdx.x;
  if (i >= n4) return;
  float4_ x = ((const float4_*)a)[i];
  float4_ y = ((const float4_*)b)[i];
  short4_ u, v;
  #pragma unroll
  for (int j=0;j<4;j++){ u[j] = (short)f2bf(x[j]); v[j] = (short)f2bf(y[j]); }
  ((short4_*)oa)[i] = u;
  ((short4_*)ob)[i] = v;
}

// ---------------- kernel 2: emb -> bf16 + tcw = softmax(emb @ embp.T) ----------------
__global__ void k_emb(const float* __restrict__ emb, const float* __restrict__ embp,
                      unsigned short* __restrict__ emb_bf, float* __restrict__ tcw){
  int wid = (blockIdx.x*256 + threadIdx.x) >> 6;
  int lane = threadIdx.x & 63;
  if (wid >= NITEMS) return;
  float4_ v = ((const float4_*)(emb + (size_t)wid*DIM))[lane];
  short4_ o;
  #pragma unroll
  for (int j=0;j<4;j++) o[j] = (short)f2bf(v[j]);
  ((short4_*)emb_bf)[(size_t)wid*64 + lane] = o;
  const float4_* pp = (const float4_*)embp;
  float4_ e0 = pp[lane], e1 = pp[64+lane], e2 = pp[128+lane];
  float d0=0.f,d1=0.f,d2=0.f;
  #pragma unroll
  for (int j=0;j<4;j++){ d0 += v[j]*e0[j]; d1 += v[j]*e1[j]; d2 += v[j]*e2[j]; }
  #pragma unroll
  for (int off=32; off; off>>=1){ d0 += __shfl_xor(d0,off); d1 += __shfl_xor(d1,off); d2 += __shfl_xor(d2,off); }
  if (lane == 0){
    float m = fmaxf(d0, fmaxf(d1,d2));
    float a0 = __expf(d0-m), a1 = __expf(d1-m), a2 = __expf(d2-m);
    float inv = 1.f/(a0+a1+a2);
    tcw[wid*3+0] = a0*inv; tcw[wid*3+1] = a1*inv; tcw[wid*3+2] = a2*inv;
  }
}

// ---------------- kernel 3: gather x (bf16) + concen softmax -> cf ----------------
__global__ void k_gather(const int* __restrict__ seq, const float* __restrict__ emb,
                         const float* __restrict__ embp, unsigned short* __restrict__ x_bf,
                         float* __restrict__ cfb){
  int wid = (blockIdx.x*256 + threadIdx.x) >> 6;   // wid = s*128 + b
  int lane = threadIdx.x & 63;
  if (wid >= NSEQ) return;
  int s = wid >> 7, b = wid & 127;
  int item = seq[s*BATCH + b];
  float4_ v = ((const float4_*)(emb + (size_t)item*DIM))[lane];
  short4_ o;
  #pragma unroll
  for (int j=0;j<4;j++) o[j] = (short)f2bf(v[j]);
  ((short4_*)x_bf)[(size_t)wid*64 + lane] = o;
  const float4_* pp = (const float4_*)embp;
  float4_ e0 = pp[lane], e1 = pp[64+lane], e2 = pp[128+lane];
  float d0=0.f,d1=0.f,d2=0.f;
  #pragma unroll
  for (int j=0;j<4;j++){ d0 += v[j]*e0[j]; d1 += v[j]*e1[j]; d2 += v[j]*e2[j]; }
  #pragma unroll
  for (int off=32; off; off>>=1){ d0 += __shfl_xor(d0,off); d1 += __shfl_xor(d1,off); d2 += __shfl_xor(d2,off); }
  if (lane == 0){
    float m = fmaxf(d0, fmaxf(d1,d2));
    float a0 = __expf((d0-m)*10.f), a1 = __expf((d1-m)*10.f), a2 = __expf((d2-m)*10.f);
    float inv = (item != 0) ? 1.f/(a0+a1+a2) : 0.f;   // mask fused in
    float c0 = a0*inv, c1 = a1*inv, c2 = a2*inv;
    cfb[wid]          = (c0 >= 0.01f) ? c0 : 0.f;
    cfb[NSEQ + wid]   = (c1 >= 0.01f) ? c1 : 0.f;
    cfb[2*NSEQ + wid] = (c2 >= 0.01f) ? c2 : 0.f;
  }
}

// ---------------- kernel 4: gi = x @ W_ih.T + b_ih  (bf16 out) ----------------
__global__ __launch_bounds__(256) void k_gi(const unsigned short* __restrict__ x_bf,
        const unsigned short* __restrict__ wih_bf, const float* __restrict__ bih,
        unsigned short* __restrict__ gi_bf){
  int p  = blockIdx.z;
  int n0 = blockIdx.x * 64;
  int m0 = blockIdx.y * 64 + (threadIdx.x >> 6) * 16;
  int lane = threadIdx.x & 63;
  int col = lane & 15, q = lane >> 4, kq = q*8;
  const unsigned short* W = wih_bf + (size_t)p*GDIM*DIM;
  const unsigned short* A = x_bf + (size_t)(m0 + col)*DIM + kq;
  float4_ z4 = {0.f,0.f,0.f,0.f};
  float4_ acc[4];
  #pragma unroll
  for (int t=0;t<4;t++) acc[t] = z4;
  #pragma unroll
  for (int kf=0; kf<8; kf++){
    short8 a = *(const short8*)(A + kf*32);
    #pragma unroll
    for (int t=0;t<4;t++){
      short8 bb = *(const short8*)(W + (size_t)(n0 + t*16 + col)*DIM + kf*32 + kq);
      acc[t] = __builtin_amdgcn_mfma_f32_16x16x32_bf16(a, bb, acc[t], 0, 0, 0);
    }
  }
  #pragma unroll
  for (int t=0;t<4;t++){
    int n = n0 + t*16 + col;
    float bv = bih[p*GDIM + n];
    #pragma unroll
    for (int i=0;i<4;i++){
      int m = m0 + 4*q + i;
      gi_bf[((size_t)p*NSEQ + m)*GDIM + n] = f2bf(acc[t][i] + bv);
    }
  }
}

// ---------------- kernel 5: 50-step PSRU recurrence, W_hh CU-resident ----------------
// grid = 24 blocks: (p, 16-batch-slice). 512 thr = 8 waves; wave w owns gate
// cols {g*256 + w*32 + [0,32)} for g=r,z,n -> computes h dims [w*32, w*32+32).
// r,z W-tiles (4 x 8 b-frags = 128 VGPRs/lane) live in registers for all 50
// steps; n-gate W tile (256x256 = 131 KB) lives in LDS, XOR-swizzled.
// h: f32 in registers (producer==consumer), bf16 XOR-swizzled LDS for MFMA A.
// LDS: [0,16384) h_bf dbuf | [16384,147456) W_n | [147456,150656) cf
// amdgpu_waves_per_eu(2,2): LDS forces 1 block/CU (2 waves/SIMD); tell the
// allocator so its budget is 256 VGPRs — round-2's launch_bounds(512,2) made
// it cap at 128 (VGPR_Count=120) and spill the 128-reg W array into the loop.
__global__ __launch_bounds__(512) __attribute__((amdgpu_waves_per_eu(2, 2)))
void k_rnn(const unsigned short* __restrict__ whh_bf,
         const unsigned short* __restrict__ gi_bf, const float* __restrict__ bhh,
         const float* __restrict__ cfb, unsigned short* __restrict__ hn_bf){
  extern __shared__ char lds[];
  float* cfs = (float*)(lds + 147456);
  int p  = blockIdx.x >> 3;
  int b0 = (blockIdx.x & 7) * 16;
  int tid = threadIdx.x;
  int w = tid >> 6, lane = tid & 63;
  int col = lane & 15;
  int q = lane >> 4;
  int kq = q * 8;
  const unsigned short* Wp = whh_bf + (size_t)p*GDIM*DIM;

  // zero h bf16 buffers
  for (int i = tid; i < 8192; i += 512) ((unsigned short*)lds)[i] = 0;
  // stage cf
  for (int i = tid; i < 800; i += 512) cfs[i] = cfb[p*NSEQ + (i>>4)*BATCH + b0 + (i&15)];
  // stage n-gate W tile (rows 512..767) into LDS with XOR swizzle
  {
    const unsigned short* Wn = Wp + (size_t)512*DIM;
    #pragma unroll
    for (int r = 0; r < 16; r++){
      int j = r*512 + tid;          // 16B-chunk index, 0..8191
      int row = j >> 5;             // 0..255
      int cb  = (j & 31) << 4;      // byte col in row, 0..496
      short8 v = *(const short8*)(Wn + (size_t)row*DIM + ((j&31)<<3));
      *(short8*)(lds + 16384 + row*512 + (cb ^ ((row&7)<<4))) = v;
    }
  }

  int gcol[6]; float bias[6];
  #pragma unroll
  for (int t=0;t<6;t++){
    gcol[t] = (t>>1)*256 + w*32 + (t&1)*16 + col;   // t: 0,1=r  2,3=z  4,5=n
    bias[t] = bhh[p*GDIM + gcol[t]];
  }
  // preload r,z W b-frags into registers (held across all 50 steps)
  short8 Bf[8][4];
  #pragma unroll
  for (int kf=0; kf<8; kf++){
    #pragma unroll
    for (int t=0;t<4;t++)
      Bf[kf][t] = *(const short8*)(Wp + ((size_t)gcol[t] << 8) + kf*32 + kq);
  }
  // LDS pointers for the two n-gate 16-col sub-tiles this wave reads
  const char* wn0 = lds + 16384 + (w*32 + col)*512;
  const char* wn1 = wn0 + 16*512;
  int swz  = (lane & 7) << 4;   // h-buffer row swizzle (row = col here)
  int swzW = (col & 7) << 4;    // W_n row swizzle (rows == col mod 8)
  float hreg[2][4];
  #pragma unroll
  for (int t=0;t<2;t++){
    #pragma unroll
    for (int i=0;i<4;i++) hreg[t][i] = 0.f;
  }
  __syncthreads();

  float4_ z4 = {0.f,0.f,0.f,0.f};
  for (int s = 0; s < S_LEN; s++){
    int rbuf = s & 1, wbuf = rbuf ^ 1;
    const unsigned short* gp = gi_bf + ((size_t)p*NSEQ + s*BATCH + b0)*GDIM;
    float giv[6][4];
    #pragma unroll
    for (int t=0;t<6;t++){
      #pragma unroll
      for (int i=0;i<4;i++)
        giv[t][i] = bf2f(gp[(size_t)(4*q+i)*GDIM + gcol[t]]);
    }
    float4_ acc[6];
    #pragma unroll
    for (int t=0;t<6;t++) acc[t] = z4;
    const char* hrow = lds + rbuf*8192 + col*512;
    #pragma unroll
    for (int kf=0; kf<8; kf++){
      int ko = (kf*64 + q*16);
      short8 a = *(const short8*)(hrow + (ko ^ swz));
      #pragma unroll
      for (int t=0;t<4;t++)
        acc[t] = __builtin_amdgcn_mfma_f32_16x16x32_bf16(a, Bf[kf][t], acc[t], 0, 0, 0);
      short8 b4 = *(const short8*)(wn0 + (ko ^ swzW));
      acc[4] = __builtin_amdgcn_mfma_f32_16x16x32_bf16(a, b4, acc[4], 0, 0, 0);
      short8 b5 = *(const short8*)(wn1 + (ko ^ swzW));
      acc[5] = __builtin_amdgcn_mfma_f32_16x16x32_bf16(a, b5, acc[5], 0, 0, 0);
    }
    #pragma unroll
    for (int t=0;t<2;t++){
      #pragma unroll
      for (int i=0;i<4;i++){
        int rb = 4*q + i;
        int d = w*32 + t*16 + col;
        float r = sigm(giv[t][i]   + acc[t][i]   + bias[t]);
        float z = sigm(giv[t+2][i] + acc[t+2][i] + bias[t+2]);
        float pre = giv[t+4][i] + r*(acc[t+4][i] + bias[t+4]);
        float n = 1.f - 2.f/(__expf(2.f*pre) + 1.f);        // tanh, NaN-safe
        float cfv = cfs[s*16 + rb];
        float ho = hreg[t][i];
        float hy = ho - cfv*z*(ho - n);
        hreg[t][i] = hy;
        *(unsigned short*)(lds + wbuf*8192 + rb*512 + ((2*d) ^ ((rb&7)<<4))) = f2bf(hy);
      }
    }
    __syncthreads();
  }
  // write final hidden state straight from registers
  #pragma unroll
  for (int t=0;t<2;t++){
    #pragma unroll
    for (int i=0;i<4;i++){
      int rb = 4*q + i;
      int d = w*32 + t*16 + col;
      hn_bf[((size_t)p*BATCH + b0 + rb)*DIM + d] = f2bf(hreg[t][i]);
    }
  }
}

// ---------------- kernel 6: scores = sum_p tcw[t,p] * (hn_p @ emb.T) ----------------
__global__ __launch_bounds__(256) void k_score(const unsigned short* __restrict__ emb_bf,
        const unsigned short* __restrict__ hn_bf, const float* __restrict__ tcw,
        float* __restrict__ out){
  int w = threadIdx.x >> 6, lane = threadIdx.x & 63;
  int col = lane & 15, q = lane >> 4, kq = q*8;
  int trow = blockIdx.x*64 + w*16 + col;
  float4_ z4 = {0.f,0.f,0.f,0.f};
  float4_ acc[3][8];
  #pragma unroll
  for (int p=0;p<3;p++){
    #pragma unroll
    for (int m=0;m<8;m++) acc[p][m] = z4;
  }
  const unsigned short* E = emb_bf + (size_t)trow*DIM + kq;
  #pragma unroll
  for (int kf=0; kf<8; kf++){
    short8 bb = *(const short8*)(E + kf*32);
    #pragma unroll
    for (int p=0;p<3;p++){
      #pragma unroll
      for (int m=0;m<8;m++){
        short8 a = *(const short8*)(hn_bf + ((size_t)p*BATCH + m*16 + col)*DIM + kf*32 + kq);
        acc[p][m] = __builtin_amdgcn_mfma_f32_16x16x32_bf16(a, bb, acc[p][m], 0, 0, 0);
      }
    }
  }
  if (trow < NITEMS){
    float w0 = tcw[trow*3+0], w1 = tcw[trow*3+1], w2 = tcw[trow*3+2];
    #pragma unroll
    for (int m=0;m<8;m++){
      #pragma unroll
      for (int i=0;i<4;i++){
        int b = m*16 + 4*q + i;
        out[(size_t)b*NITEMS + trow] = w0*acc[0][m][i] + w1*acc[1][m][i] + w2*acc[2][m][i];
      }
    }
  }
}

extern "C" void kernel_launch(void* const* d_in, const int* in_sizes, int n_in,
                              void* d_out, int out_size, void* d_ws, size_t ws_size,
                              hipStream_t stream) {
  const int*   seq  = (const int*)d_in[0];
  const float* emb  = (const float*)d_in[1];
  const float* embp = (const float*)d_in[2];
  const float* wih  = (const float*)d_in[3];
  const float* whh  = (const float*)d_in[4];
  const float* bih  = (const float*)d_in[5];
  const float* bhh  = (const float*)d_in[6];
  float* out = (float*)d_out;

  char* ws = (char*)d_ws;
  size_t off = 0;
  auto alloc = [&](size_t bytes) -> void* {
    void* r = ws + off; off += (bytes + 255) & ~(size_t)255; return r;
  };
  unsigned short* emb_bf = (unsigned short*)alloc((size_t)NPAD*DIM*2);
  unsigned short* x_bf   = (unsigned short*)alloc((size_t)NSEQ*DIM*2);
  unsigned short* wih_bf = (unsigned short*)alloc((size_t)3*GDIM*DIM*2);
  unsigned short* whh_bf = (unsigned short*)alloc((size_t)3*GDIM*DIM*2);
  unsigned short* gi_bf  = (unsigned short*)alloc((size_t)3*NSEQ*GDIM*2);
  float* tcw = (float*)alloc((size_t)NITEMS*3*4);
  float* cfb = (float*)alloc((size_t)3*NSEQ*4);
  unsigned short* hn_bf = (unsigned short*)alloc((size_t)3*BATCH*DIM*2);

  k_conv_w<<<1152, 256, 0, stream>>>(wih, whh, wih_bf, whh_bf, 3*GDIM*DIM/4);
  k_emb<<<(NITEMS+3)/4, 256, 0, stream>>>(emb, embp, emb_bf, tcw);
  k_gather<<<NSEQ/4, 256, 0, stream>>>(seq, emb, embp, x_bf, cfb);
  dim3 gg(GDIM/64, NSEQ/64, 3);
  k_gi<<<gg, 256, 0, stream>>>(x_bf, wih_bf, bih, gi_bf);

  (void)hipFuncSetAttribute((const void*)k_rnn,
        hipFuncAttributeMaxDynamicSharedMemorySize, 150656);
  k_rnn<<<24, 512, 150656, stream>>>(whh_bf, gi_bf, bhh, cfb, hn_bf);

  k_score<<<NPAD/64, 256, 0, stream>>>(emb_bf, hn_bf, tcw, out);
}

// Round 4
// 361.122 us; speedup vs baseline: 1.4471x; 1.4471x over previous
//
#include <hip/hip_runtime.h>
#include <hip/hip_bf16.h>

#define S_LEN 50
#define BATCH 128
#define DIM 256
#define NITEMS 50001
#define NPAD 50048
#define GDIM 768
#define NSEQ 6400  // S_LEN*BATCH

typedef __attribute__((ext_vector_type(8))) short short8;
typedef __attribute__((ext_vector_type(4))) short short4_;
typedef __attribute__((ext_vector_type(4))) float float4_;

static __device__ __forceinline__ unsigned short f2bf(float x){
  union { float f; unsigned u; } v; v.f = x;
  unsigned r = v.u + 0x7FFFu + ((v.u >> 16) & 1u);
  return (unsigned short)(r >> 16);
}
static __device__ __forceinline__ float bf2f(unsigned short h){
  union { unsigned u; float f; } v; v.u = ((unsigned)h) << 16;
  return v.f;
}
static __device__ __forceinline__ float sigm(float x){ return 1.f/(1.f + __expf(-x)); }

// ---------------- kernel 1: convert W_ih / W_hh to bf16 ----------------
__global__ void k_conv_w(const float* __restrict__ a, const float* __restrict__ b,
                         unsigned short* __restrict__ oa, unsigned short* __restrict__ ob, int n4){
  int i = blockIdx.x*256 + threadIdx.x;
  if (i >= n4) return;
  float4_ x = ((const float4_*)a)[i];
  float4_ y = ((const float4_*)b)[i];
  short4_ u, v;
  #pragma unroll
  for (int j=0;j<4;j++){ u[j] = (short)f2bf(x[j]); v[j] = (short)f2bf(y[j]); }
  ((short4_*)oa)[i] = u;
  ((short4_*)ob)[i] = v;
}

// ---------------- kernel 2: emb -> bf16 + tcw = softmax(emb @ embp.T) ----------------
__global__ void k_emb(const float* __restrict__ emb, const float* __restrict__ embp,
                      unsigned short* __restrict__ emb_bf, float* __restrict__ tcw){
  int wid = (blockIdx.x*256 + threadIdx.x) >> 6;
  int lane = threadIdx.x & 63;
  if (wid >= NITEMS) return;
  float4_ v = ((const float4_*)(emb + (size_t)wid*DIM))[lane];
  short4_ o;
  #pragma unroll
  for (int j=0;j<4;j++) o[j] = (short)f2bf(v[j]);
  ((short4_*)emb_bf)[(size_t)wid*64 + lane] = o;
  const float4_* pp = (const float4_*)embp;
  float4_ e0 = pp[lane], e1 = pp[64+lane], e2 = pp[128+lane];
  float d0=0.f,d1=0.f,d2=0.f;
  #pragma unroll
  for (int j=0;j<4;j++){ d0 += v[j]*e0[j]; d1 += v[j]*e1[j]; d2 += v[j]*e2[j]; }
  #pragma unroll
  for (int off=32; off; off>>=1){ d0 += __shfl_xor(d0,off); d1 += __shfl_xor(d1,off); d2 += __shfl_xor(d2,off); }
  if (lane == 0){
    float m = fmaxf(d0, fmaxf(d1,d2));
    float a0 = __expf(d0-m), a1 = __expf(d1-m), a2 = __expf(d2-m);
    float inv = 1.f/(a0+a1+a2);
    tcw[wid*3+0] = a0*inv; tcw[wid*3+1] = a1*inv; tcw[wid*3+2] = a2*inv;
  }
}

// ---------------- kernel 3: gather x (bf16) + concen softmax -> cf ----------------
__global__ void k_gather(const int* __restrict__ seq, const float* __restrict__ emb,
                         const float* __restrict__ embp, unsigned short* __restrict__ x_bf,
                         float* __restrict__ cfb){
  int wid = (blockIdx.x*256 + threadIdx.x) >> 6;   // wid = s*128 + b
  int lane = threadIdx.x & 63;
  if (wid >= NSEQ) return;
  int s = wid >> 7, b = wid & 127;
  int item = seq[s*BATCH + b];
  float4_ v = ((const float4_*)(emb + (size_t)item*DIM))[lane];
  short4_ o;
  #pragma unroll
  for (int j=0;j<4;j++) o[j] = (short)f2bf(v[j]);
  ((short4_*)x_bf)[(size_t)wid*64 + lane] = o;
  const float4_* pp = (const float4_*)embp;
  float4_ e0 = pp[lane], e1 = pp[64+lane], e2 = pp[128+lane];
  float d0=0.f,d1=0.f,d2=0.f;
  #pragma unroll
  for (int j=0;j<4;j++){ d0 += v[j]*e0[j]; d1 += v[j]*e1[j]; d2 += v[j]*e2[j]; }
  #pragma unroll
  for (int off=32; off; off>>=1){ d0 += __shfl_xor(d0,off); d1 += __shfl_xor(d1,off); d2 += __shfl_xor(d2,off); }
  if (lane == 0){
    float m = fmaxf(d0, fmaxf(d1,d2));
    float a0 = __expf((d0-m)*10.f), a1 = __expf((d1-m)*10.f), a2 = __expf((d2-m)*10.f);
    float inv = (item != 0) ? 1.f/(a0+a1+a2) : 0.f;   // mask fused in
    float c0 = a0*inv, c1 = a1*inv, c2 = a2*inv;
    cfb[wid]          = (c0 >= 0.01f) ? c0 : 0.f;
    cfb[NSEQ + wid]   = (c1 >= 0.01f) ? c1 : 0.f;
    cfb[2*NSEQ + wid] = (c2 >= 0.01f) ? c2 : 0.f;
  }
}

// ---------------- kernel 4: gi = x @ W_ih.T + b_ih -> thread-major gi2 ----------------
// gi2 layout: [p][s][slice(8)][tid(512)][24], so that k_rnn thread tid reads its
// 24 gate pre-activations for step s as 3 contiguous short8 loads (48B, aligned).
// element index t*4+i maps to gate col (t>>1)*256 + w*32 + (t&1)*16 + (lane&15),
// batch row 4*(lane>>4)+i, with tid = w*64+lane.
__global__ __launch_bounds__(256) void k_gi(const unsigned short* __restrict__ x_bf,
        const unsigned short* __restrict__ wih_bf, const float* __restrict__ bih,
        unsigned short* __restrict__ gi2){
  int p  = blockIdx.z;
  int wv = threadIdx.x >> 6;
  int m0 = blockIdx.y * 64 + wv * 16;
  int lane = threadIdx.x & 63;
  int col = lane & 15, q = lane >> 4, kq = q*8;
  const unsigned short* W = wih_bf + (size_t)p*GDIM*DIM;
  const unsigned short* A = x_bf + (size_t)(m0 + col)*DIM + kq;
  float4_ z4 = {0.f,0.f,0.f,0.f};
  float4_ acc[4];
  #pragma unroll
  for (int t=0;t<4;t++) acc[t] = z4;
  #pragma unroll
  for (int kf=0; kf<8; kf++){
    short8 a = *(const short8*)(A + kf*32);
    #pragma unroll
    for (int t=0;t<4;t++){
      short8 bb = *(const short8*)(W + (size_t)(blockIdx.x*64 + t*16 + col)*DIM + kf*32 + kq);
      acc[t] = __builtin_amdgcn_mfma_f32_16x16x32_bf16(a, bb, acc[t], 0, 0, 0);
    }
  }
  int s     = blockIdx.y >> 1;
  int slice = (blockIdx.y & 1)*4 + wv;
  size_t tbase = ((((size_t)p*S_LEN + s)*8 + slice)*512 + q*16 + col)*24;
  #pragma unroll
  for (int t=0;t<4;t++){
    int nn = blockIdx.x*4 + t;       // n/16
    int g  = nn >> 4;                // gate
    int wc = (nn >> 1) & 7;          // consumer wave
    int tt = nn & 1;
    int n  = nn*16 + col;
    float bv = bih[p*GDIM + n];
    size_t dst = tbase + (size_t)wc*(64*24) + (size_t)(g*2+tt)*4;
    #pragma unroll
    for (int i=0;i<4;i++)
      gi2[dst + i] = f2bf(acc[t][i] + bv);
  }
}

// ---------------- kernel 5: 50-step PSRU recurrence, W_hh truly CU-resident ----------------
// grid = 24 blocks: (p, 16-batch-slice). 512 thr = 8 waves; wave w owns gate
// cols {g*256 + w*32 + [0,32)} for g=r,z,n -> computes h dims [w*32, w*32+32).
// r,z W-tiles: 32 short8/lane pinned into AGPRs via `asm volatile("" : "+a")`
// AFTER the preload — volatile asm cannot be rematerialized, so the allocator
// must keep the 128 AGPRs live (rounds 2/3 failed because the compiler chose
// to re-load the "register" array from L2 every step: VGPR_Count stuck at 120).
// n-gate W tile (256x256 = 131 KB) in LDS, XOR-swizzled. h f32 in regs, bf16
// XOR-swizzled LDS dbuf for MFMA A. gi read as 3 coalesced short8/step,
// prefetched one step ahead.
// LDS: [0,16384) h_bf dbuf | [16384,147456) W_n | [147456,150656) cf
__global__ __launch_bounds__(512) __attribute__((amdgpu_waves_per_eu(2, 2)))
void k_rnn(const unsigned short* __restrict__ whh_bf,
         const unsigned short* __restrict__ gi2, const float* __restrict__ bhh,
         const float* __restrict__ cfb, unsigned short* __restrict__ hn_bf){
  extern __shared__ char lds[];
  float* cfs = (float*)(lds + 147456);
  int p  = blockIdx.x >> 3;
  int b0 = (blockIdx.x & 7) * 16;
  int tid = threadIdx.x;
  int w = tid >> 6, lane = tid & 63;
  int col = lane & 15;
  int q = lane >> 4;
  int kq = q * 8;
  const unsigned short* Wp = whh_bf + (size_t)p*GDIM*DIM;

  // zero h bf16 buffers
  for (int i = tid; i < 8192; i += 512) ((unsigned short*)lds)[i] = 0;
  // stage cf
  for (int i = tid; i < 800; i += 512) cfs[i] = cfb[p*NSEQ + (i>>4)*BATCH + b0 + (i&15)];
  // stage n-gate W tile (rows 512..767) into LDS with XOR swizzle
  {
    const unsigned short* Wn = Wp + (size_t)512*DIM;
    #pragma unroll
    for (int r = 0; r < 16; r++){
      int j = r*512 + tid;          // 16B-chunk index, 0..8191
      int row = j >> 5;             // 0..255
      int cb  = (j & 31) << 4;      // byte col in row, 0..496
      short8 v = *(const short8*)(Wn + (size_t)row*DIM + ((j&31)<<3));
      *(short8*)(lds + 16384 + row*512 + (cb ^ ((row&7)<<4))) = v;
    }
  }

  int gcol[6]; float bias[6];
  #pragma unroll
  for (int t=0;t<6;t++){
    gcol[t] = (t>>1)*256 + w*32 + (t&1)*16 + col;   // t: 0,1=r  2,3=z  4,5=n
    bias[t] = bhh[p*GDIM + gcol[t]];
  }
  // preload r,z W b-frags and PIN into AGPRs (unrematerializable)
  short8 Bf[8][4];
  #pragma unroll
  for (int kf=0; kf<8; kf++){
    #pragma unroll
    for (int t=0;t<4;t++){
      Bf[kf][t] = *(const short8*)(Wp + ((size_t)gcol[t] << 8) + kf*32 + kq);
      asm volatile("" : "+a"(Bf[kf][t]));
    }
  }
  // LDS pointers for the two n-gate 16-col sub-tiles this wave reads
  const char* wn0 = lds + 16384 + (w*32 + col)*512;
  const char* wn1 = wn0 + 16*512;
  int swz  = (lane & 7) << 4;   // h-buffer row swizzle (row = col here)
  int swzW = (col & 7) << 4;    // W_n row swizzle (rows == col mod 8)
  float hreg[2][4];
  #pragma unroll
  for (int t=0;t<2;t++){
    #pragma unroll
    for (int i=0;i<4;i++) hreg[t][i] = 0.f;
  }
  // gi pipeline: 3 contiguous short8 per step, prefetch s+1 during step s
  const size_t GSTRIDE = (size_t)8*512*24;
  const unsigned short* gbase =
      gi2 + (((size_t)p*S_LEN*8 + (b0>>4))*512 + tid)*24;
  short8 cur0 = *(const short8*)(gbase);
  short8 cur1 = *(const short8*)(gbase + 8);
  short8 cur2 = *(const short8*)(gbase + 16);
  __syncthreads();

  float4_ z4 = {0.f,0.f,0.f,0.f};
  for (int s = 0; s < S_LEN; s++){
    int rbuf = s & 1, wbuf = rbuf ^ 1;
    int sn = (s+1 < S_LEN) ? s+1 : 0;            // clamp: dummy load on last step
    const unsigned short* gnp = gbase + (size_t)sn*GSTRIDE;
    short8 nxt0 = *(const short8*)(gnp);
    short8 nxt1 = *(const short8*)(gnp + 8);
    short8 nxt2 = *(const short8*)(gnp + 16);
    float4_ acc[6];
    #pragma unroll
    for (int t=0;t<6;t++) acc[t] = z4;
    const char* hrow = lds + rbuf*8192 + col*512;
    #pragma unroll
    for (int kf=0; kf<8; kf++){
      int ko = (kf*64 + q*16);
      short8 a = *(const short8*)(hrow + (ko ^ swz));
      #pragma unroll
      for (int t=0;t<4;t++)
        acc[t] = __builtin_amdgcn_mfma_f32_16x16x32_bf16(a, Bf[kf][t], acc[t], 0, 0, 0);
      short8 b4 = *(const short8*)(wn0 + (ko ^ swzW));
      acc[4] = __builtin_amdgcn_mfma_f32_16x16x32_bf16(a, b4, acc[4], 0, 0, 0);
      short8 b5 = *(const short8*)(wn1 + (ko ^ swzW));
      acc[5] = __builtin_amdgcn_mfma_f32_16x16x32_bf16(a, b5, acc[5], 0, 0, 0);
    }
    #pragma unroll
    for (int t=0;t<2;t++){
      #pragma unroll
      for (int i=0;i<4;i++){
        int rb = 4*q + i;
        int d = w*32 + t*16 + col;
        float gr = bf2f((unsigned short)cur0[t*4+i]);
        float gz = bf2f((unsigned short)cur1[t*4+i]);
        float gn_ = bf2f((unsigned short)cur2[t*4+i]);
        float r = sigm(gr + acc[t][i]   + bias[t]);
        float z = sigm(gz + acc[t+2][i] + bias[t+2]);
        float pre = gn_ + r*(acc[t+4][i] + bias[t+4]);
        float n = 1.f - 2.f/(__expf(2.f*pre) + 1.f);        // tanh, NaN-safe
        float cfv = cfs[s*16 + rb];
        float ho = hreg[t][i];
        float hy = ho - cfv*z*(ho - n);
        hreg[t][i] = hy;
        *(unsigned short*)(lds + wbuf*8192 + rb*512 + ((2*d) ^ ((rb&7)<<4))) = f2bf(hy);
      }
    }
    cur0 = nxt0; cur1 = nxt1; cur2 = nxt2;
    __syncthreads();
  }
  // write final hidden state straight from registers
  #pragma unroll
  for (int t=0;t<2;t++){
    #pragma unroll
    for (int i=0;i<4;i++){
      int rb = 4*q + i;
      int d = w*32 + t*16 + col;
      hn_bf[((size_t)p*BATCH + b0 + rb)*DIM + d] = f2bf(hreg[t][i]);
    }
  }
}

// ---------------- kernel 6: scores = sum_p tcw[t,p] * (hn_p @ emb.T) ----------------
__global__ __launch_bounds__(256) void k_score(const unsigned short* __restrict__ emb_bf,
        const unsigned short* __restrict__ hn_bf, const float* __restrict__ tcw,
        float* __restrict__ out){
  int w = threadIdx.x >> 6, lane = threadIdx.x & 63;
  int col = lane & 15, q = lane >> 4, kq = q*8;
  int trow = blockIdx.x*64 + w*16 + col;
  float4_ z4 = {0.f,0.f,0.f,0.f};
  float4_ acc[3][8];
  #pragma unroll
  for (int p=0;p<3;p++){
    #pragma unroll
    for (int m=0;m<8;m++) acc[p][m] = z4;
  }
  const unsigned short* E = emb_bf + (size_t)trow*DIM + kq;
  #pragma unroll
  for (int kf=0; kf<8; kf++){
    short8 bb = *(const short8*)(E + kf*32);
    #pragma unroll
    for (int p=0;p<3;p++){
      #pragma unroll
      for (int m=0;m<8;m++){
        short8 a = *(const short8*)(hn_bf + ((size_t)p*BATCH + m*16 + col)*DIM + kf*32 + kq);
        acc[p][m] = __builtin_amdgcn_mfma_f32_16x16x32_bf16(a, bb, acc[p][m], 0, 0, 0);
      }
    }
  }
  if (trow < NITEMS){
    float w0 = tcw[trow*3+0], w1 = tcw[trow*3+1], w2 = tcw[trow*3+2];
    #pragma unroll
    for (int m=0;m<8;m++){
      #pragma unroll
      for (int i=0;i<4;i++){
        int b = m*16 + 4*q + i;
        out[(size_t)b*NITEMS + trow] = w0*acc[0][m][i] + w1*acc[1][m][i] + w2*acc[2][m][i];
      }
    }
  }
}

extern "C" void kernel_launch(void* const* d_in, const int* in_sizes, int n_in,
                              void* d_out, int out_size, void* d_ws, size_t ws_size,
                              hipStream_t stream) {
  const int*   seq  = (const int*)d_in[0];
  const float* emb  = (const float*)d_in[1];
  const float* embp = (const float*)d_in[2];
  const float* wih  = (const float*)d_in[3];
  const float* whh  = (const float*)d_in[4];
  const float* bih  = (const float*)d_in[5];
  const float* bhh  = (const float*)d_in[6];
  float* out = (float*)d_out;

  char* ws = (char*)d_ws;
  size_t off = 0;
  auto alloc = [&](size_t bytes) -> void* {
    void* r = ws + off; off += (bytes + 255) & ~(size_t)255; return r;
  };
  unsigned short* emb_bf = (unsigned short*)alloc((size_t)NPAD*DIM*2);
  unsigned short* x_bf   = (unsigned short*)alloc((size_t)NSEQ*DIM*2);
  unsigned short* wih_bf = (unsigned short*)alloc((size_t)3*GDIM*DIM*2);
  unsigned short* whh_bf = (unsigned short*)alloc((size_t)3*GDIM*DIM*2);
  unsigned short* gi2    = (unsigned short*)alloc((size_t)3*NSEQ*GDIM*2);
  float* tcw = (float*)alloc((size_t)NITEMS*3*4);
  float* cfb = (float*)alloc((size_t)3*NSEQ*4);
  unsigned short* hn_bf = (unsigned short*)alloc((size_t)3*BATCH*DIM*2);

  k_conv_w<<<1152, 256, 0, stream>>>(wih, whh, wih_bf, whh_bf, 3*GDIM*DIM/4);
  k_emb<<<(NITEMS+3)/4, 256, 0, stream>>>(emb, embp, emb_bf, tcw);
  k_gather<<<NSEQ/4, 256, 0, stream>>>(seq, emb, embp, x_bf, cfb);
  dim3 gg(GDIM/64, NSEQ/64, 3);
  k_gi<<<gg, 256, 0, stream>>>(x_bf, wih_bf, bih, gi2);

  (void)hipFuncSetAttribute((const void*)k_rnn,
        hipFuncAttributeMaxDynamicSharedMemorySize, 150656);
  k_rnn<<<24, 512, 150656, stream>>>(whh_bf, gi2, bhh, cfb, hn_bf);

  k_score<<<NPAD/64, 256, 0, stream>>>(emb_bf, hn_bf, tcw, out);
}

// Round 5
// 339.054 us; speedup vs baseline: 1.5413x; 1.0651x over previous
//
#include <hip/hip_runtime.h>
#include <hip/hip_bf16.h>

#define S_LEN 50
#define BATCH 128
#define DIM 256
#define NITEMS 50001
#define NPAD 50048
#define GDIM 768
#define NSEQ 6400  // S_LEN*BATCH

typedef __attribute__((ext_vector_type(8))) short short8;
typedef __attribute__((ext_vector_type(4))) short short4_;
typedef __attribute__((ext_vector_type(4))) float float4_;

static __device__ __forceinline__ unsigned short f2bf(float x){
  union { float f; unsigned u; } v; v.f = x;
  unsigned r = v.u + 0x7FFFu + ((v.u >> 16) & 1u);
  return (unsigned short)(r >> 16);
}
static __device__ __forceinline__ float bf2f(unsigned short h){
  union { unsigned u; float f; } v; v.u = ((unsigned)h) << 16;
  return v.f;
}
static __device__ __forceinline__ float sigm(float x){ return 1.f/(1.f + __expf(-x)); }

// ---------------- kernel 1: convert W_ih / W_hh to bf16 ----------------
__global__ void k_conv_w(const float* __restrict__ a, const float* __restrict__ b,
                         unsigned short* __restrict__ oa, unsigned short* __restrict__ ob, int n4){
  int i = blockIdx.x*256 + threadIdx.x;
  if (i >= n4) return;
  float4_ x = ((const float4_*)a)[i];
  float4_ y = ((const float4_*)b)[i];
  short4_ u, v;
  #pragma unroll
  for (int j=0;j<4;j++){ u[j] = (short)f2bf(x[j]); v[j] = (short)f2bf(y[j]); }
  ((short4_*)oa)[i] = u;
  ((short4_*)ob)[i] = v;
}

// ---------------- kernel 2: emb -> bf16 + tcw = softmax(emb @ embp.T) ----------------
__global__ void k_emb(const float* __restrict__ emb, const float* __restrict__ embp,
                      unsigned short* __restrict__ emb_bf, float* __restrict__ tcw){
  int wid = (blockIdx.x*256 + threadIdx.x) >> 6;
  int lane = threadIdx.x & 63;
  if (wid >= NITEMS) return;
  float4_ v = ((const float4_*)(emb + (size_t)wid*DIM))[lane];
  short4_ o;
  #pragma unroll
  for (int j=0;j<4;j++) o[j] = (short)f2bf(v[j]);
  ((short4_*)emb_bf)[(size_t)wid*64 + lane] = o;
  const float4_* pp = (const float4_*)embp;
  float4_ e0 = pp[lane], e1 = pp[64+lane], e2 = pp[128+lane];
  float d0=0.f,d1=0.f,d2=0.f;
  #pragma unroll
  for (int j=0;j<4;j++){ d0 += v[j]*e0[j]; d1 += v[j]*e1[j]; d2 += v[j]*e2[j]; }
  #pragma unroll
  for (int off=32; off; off>>=1){ d0 += __shfl_xor(d0,off); d1 += __shfl_xor(d1,off); d2 += __shfl_xor(d2,off); }
  if (lane == 0){
    float m = fmaxf(d0, fmaxf(d1,d2));
    float a0 = __expf(d0-m), a1 = __expf(d1-m), a2 = __expf(d2-m);
    float inv = 1.f/(a0+a1+a2);
    tcw[wid*3+0] = a0*inv; tcw[wid*3+1] = a1*inv; tcw[wid*3+2] = a2*inv;
  }
}

// ---------------- kernel 3: gather x (bf16) + concen softmax -> cf ----------------
__global__ void k_gather(const int* __restrict__ seq, const float* __restrict__ emb,
                         const float* __restrict__ embp, unsigned short* __restrict__ x_bf,
                         float* __restrict__ cfb){
  int wid = (blockIdx.x*256 + threadIdx.x) >> 6;   // wid = s*128 + b
  int lane = threadIdx.x & 63;
  if (wid >= NSEQ) return;
  int s = wid >> 7, b = wid & 127;
  int item = seq[s*BATCH + b];
  float4_ v = ((const float4_*)(emb + (size_t)item*DIM))[lane];
  short4_ o;
  #pragma unroll
  for (int j=0;j<4;j++) o[j] = (short)f2bf(v[j]);
  ((short4_*)x_bf)[(size_t)wid*64 + lane] = o;
  const float4_* pp = (const float4_*)embp;
  float4_ e0 = pp[lane], e1 = pp[64+lane], e2 = pp[128+lane];
  float d0=0.f,d1=0.f,d2=0.f;
  #pragma unroll
  for (int j=0;j<4;j++){ d0 += v[j]*e0[j]; d1 += v[j]*e1[j]; d2 += v[j]*e2[j]; }
  #pragma unroll
  for (int off=32; off; off>>=1){ d0 += __shfl_xor(d0,off); d1 += __shfl_xor(d1,off); d2 += __shfl_xor(d2,off); }
  if (lane == 0){
    float m = fmaxf(d0, fmaxf(d1,d2));
    float a0 = __expf((d0-m)*10.f), a1 = __expf((d1-m)*10.f), a2 = __expf((d2-m)*10.f);
    float inv = (item != 0) ? 1.f/(a0+a1+a2) : 0.f;   // mask fused in
    float c0 = a0*inv, c1 = a1*inv, c2 = a2*inv;
    cfb[wid]          = (c0 >= 0.01f) ? c0 : 0.f;
    cfb[NSEQ + wid]   = (c1 >= 0.01f) ? c1 : 0.f;
    cfb[2*NSEQ + wid] = (c2 >= 0.01f) ? c2 : 0.f;
  }
}

// ---------------- kernel 4: gi = x @ W_ih.T + biases -> gi2 ----------------
// gi2 layout (elems): idx = X*12288 + (g*16 + wc*2 + tt)*256 + lane*4 + i,
// X = (p*S+s)*8+slice. Producer wave stores are 512B contiguous (short4/lane);
// consumer (k_rnn) reads 6x 8B/lane, also 512B contiguous per wave.
// b_ih folded for all gates; b_hh folded for r,z (n's b_hh multiplies by r later).
__global__ __launch_bounds__(256) void k_gi(const unsigned short* __restrict__ x_bf,
        const unsigned short* __restrict__ wih_bf, const float* __restrict__ bih,
        const float* __restrict__ bhh, unsigned short* __restrict__ gi2){
  int p  = blockIdx.z;
  int wv = threadIdx.x >> 6;
  int m0 = blockIdx.y * 64 + wv * 16;
  int lane = threadIdx.x & 63;
  int col = lane & 15, q = lane >> 4, kq = q*8;
  const unsigned short* W = wih_bf + (size_t)p*GDIM*DIM;
  const unsigned short* A = x_bf + (size_t)(m0 + col)*DIM + kq;
  float4_ z4 = {0.f,0.f,0.f,0.f};
  float4_ acc[4];
  #pragma unroll
  for (int t=0;t<4;t++) acc[t] = z4;
  #pragma unroll
  for (int kf=0; kf<8; kf++){
    short8 a = *(const short8*)(A + kf*32);
    #pragma unroll
    for (int t=0;t<4;t++){
      short8 bb = *(const short8*)(W + (size_t)(blockIdx.x*64 + t*16 + col)*DIM + kf*32 + kq);
      acc[t] = __builtin_amdgcn_mfma_f32_16x16x32_bf16(a, bb, acc[t], 0, 0, 0);
    }
  }
  int s     = blockIdx.y >> 1;
  int slice = (blockIdx.y & 1)*4 + wv;
  size_t X = (size_t)(p*S_LEN + s)*8 + slice;
  int g = blockIdx.x >> 2;               // gate, uniform per block
  #pragma unroll
  for (int t=0;t<4;t++){
    int nn = blockIdx.x*4 + t;           // n/16
    int wc = (nn >> 1) & 7;              // consumer wave
    int tt = nn & 1;
    int n  = nn*16 + col;
    float bv = bih[p*GDIM + n] + ((g < 2) ? bhh[p*GDIM + n] : 0.f);
    short4_ ov;
    #pragma unroll
    for (int i=0;i<4;i++) ov[i] = (short)f2bf(acc[t][i] + bv);
    *(short4_*)(gi2 + X*12288 + (size_t)(g*16 + wc*2 + tt)*256 + lane*4) = ov;
  }
}

// ---------------- kernel 5: 50-step PSRU recurrence, W_hh CU-resident ----------------
// grid = 24 blocks: (p, 16-batch-slice). 512 thr = 8 waves; wave w owns gate
// cols {g*256 + w*32 + [0,32)} -> h dims [w*32, w*32+32).
// r,z W-tiles: 128 AGPRs/lane, pinned via asm volatile "+a" (round-4 proven).
// n-gate W tile in LDS as 16B chunks [kf][row][qs], content col-block
// qs ^ ((row>>1)&3): quarter-wave reads hit all 8 16B-slots, 2 lanes each
// (conflict floor) — fixes round-4's 921600 conflicts/dispatch.
// gi2 read as 6 coalesced 8B loads/step, prefetched one step ahead.
// LDS: [0,16384) h_bf dbuf | [16384,147456) W_n | [147456,150656) cf
__global__ __launch_bounds__(512) __attribute__((amdgpu_waves_per_eu(2, 2)))
void k_rnn(const unsigned short* __restrict__ whh_bf,
         const unsigned short* __restrict__ gi2, const float* __restrict__ bhh,
         const float* __restrict__ cfb, unsigned short* __restrict__ hn_bf){
  extern __shared__ char lds[];
  float* cfs = (float*)(lds + 147456);
  int p  = blockIdx.x >> 3;
  int b0 = (blockIdx.x & 7) * 16;
  int tid = threadIdx.x;
  int w = tid >> 6, lane = tid & 63;
  int col = lane & 15;
  int q = lane >> 4;
  int kq = q * 8;
  const unsigned short* Wp = whh_bf + (size_t)p*GDIM*DIM;

  // zero h bf16 buffers
  for (int i = tid; i < 8192; i += 512) ((unsigned short*)lds)[i] = 0;
  // stage cf
  for (int i = tid; i < 800; i += 512) cfs[i] = cfb[p*NSEQ + (i>>4)*BATCH + b0 + (i&15)];
  // stage n-gate W tile (rows 512..767): chunk j=(kf*256+row)*4+qs at lds+16384+j*16,
  // content = W[512+row][kf*32 + (qs^((row>>1)&3))*8 ..+8)
  {
    const unsigned short* Wn = Wp + (size_t)512*DIM;
    #pragma unroll
    for (int r = 0; r < 16; r++){
      int j = r*512 + tid;          // 0..8191
      int kf = j >> 10, row = (j >> 2) & 255, qs = j & 3;
      short8 v = *(const short8*)(Wn + (size_t)row*DIM + kf*32 + ((qs ^ ((row>>1)&3)) << 3));
      *(short8*)(lds + 16384 + j*16) = v;
    }
  }

  // n-gate biases (b_hh, multiplied by r in the cell)
  float bias_n0 = bhh[p*GDIM + 512 + w*32 + col];
  float bias_n1 = bhh[p*GDIM + 512 + w*32 + 16 + col];

  // preload r,z W b-frags and PIN into AGPRs (unrematerializable)
  short8 Bf[8][4];
  #pragma unroll
  for (int kf=0; kf<8; kf++){
    #pragma unroll
    for (int t=0;t<4;t++){
      int gc = (t>>1)*256 + w*32 + (t&1)*16 + col;
      Bf[kf][t] = *(const short8*)(Wp + ((size_t)gc << 8) + kf*32 + kq);
      asm volatile("" : "+a"(Bf[kf][t]));
    }
  }
  // W_n LDS base pointers for this thread's two 16-col subtiles
  const char* wn0 = lds + 16384 + (size_t)(w*32 + col)*64 + ((q ^ ((col>>1)&3)) << 4);
  const char* wn1 = wn0 + 16*64;
  int swz  = (lane & 7) << 4;   // h-buffer swizzle (row = col)
  float hreg[2][4];
  #pragma unroll
  for (int t=0;t<2;t++){
    #pragma unroll
    for (int i=0;i<4;i++) hreg[t][i] = 0.f;
  }
  // gi pipeline: 6 short4 loads per step, prefetch s+1 during step s
  const size_t GSTRIDE = (size_t)8*12288;   // per-s elems
  const unsigned short* gbase =
      gi2 + ((size_t)p*S_LEN*8 + (b0>>4))*12288 + (size_t)(w*2)*256 + lane*4;
  short4_ cur[6], nxt[6];
  #pragma unroll
  for (int t=0;t<6;t++)
    cur[t] = *(const short4_*)(gbase + (t>>1)*4096 + (t&1)*256);
  __syncthreads();

  float4_ z4 = {0.f,0.f,0.f,0.f};
  for (int s = 0; s < S_LEN; s++){
    int rbuf = s & 1, wbuf = rbuf ^ 1;
    int sn = (s+1 < S_LEN) ? s+1 : 0;            // clamp: dummy load on last step
    const unsigned short* gnp = gbase + (size_t)sn*GSTRIDE;
    #pragma unroll
    for (int t=0;t<6;t++)
      nxt[t] = *(const short4_*)(gnp + (t>>1)*4096 + (t&1)*256);
    float4_ acc[6];
    #pragma unroll
    for (int t=0;t<6;t++) acc[t] = z4;
    const char* hrow = lds + rbuf*8192 + col*512;
    #pragma unroll
    for (int kf=0; kf<8; kf++){
      int ko = (kf*64 + q*16);
      short8 a = *(const short8*)(hrow + (ko ^ swz));
      #pragma unroll
      for (int t=0;t<4;t++)
        acc[t] = __builtin_amdgcn_mfma_f32_16x16x32_bf16(a, Bf[kf][t], acc[t], 0, 0, 0);
      short8 b4 = *(const short8*)(wn0 + kf*16384);
      acc[4] = __builtin_amdgcn_mfma_f32_16x16x32_bf16(a, b4, acc[4], 0, 0, 0);
      short8 b5 = *(const short8*)(wn1 + kf*16384);
      acc[5] = __builtin_amdgcn_mfma_f32_16x16x32_bf16(a, b5, acc[5], 0, 0, 0);
    }
    float4_ cfv = *(const float4_*)(cfs + s*16 + 4*q);
    #pragma unroll
    for (int t=0;t<2;t++){
      float bn = t ? bias_n1 : bias_n0;
      #pragma unroll
      for (int i=0;i<4;i++){
        int rb = 4*q + i;
        int d = w*32 + t*16 + col;
        float r = sigm(bf2f((unsigned short)cur[t][i])   + acc[t][i]);
        float z = sigm(bf2f((unsigned short)cur[2+t][i]) + acc[2+t][i]);
        float pre = bf2f((unsigned short)cur[4+t][i]) + r*(acc[4+t][i] + bn);
        float n = 1.f - 2.f/(__expf(2.f*pre) + 1.f);        // tanh, NaN-safe
        float ho = hreg[t][i];
        float hy = ho - cfv[i]*z*(ho - n);
        hreg[t][i] = hy;
        *(unsigned short*)(lds + wbuf*8192 + rb*512 + ((2*d) ^ ((rb&7)<<4))) = f2bf(hy);
      }
    }
    #pragma unroll
    for (int t=0;t<6;t++) cur[t] = nxt[t];
    __syncthreads();
  }
  // write final hidden state straight from registers
  #pragma unroll
  for (int t=0;t<2;t++){
    #pragma unroll
    for (int i=0;i<4;i++){
      int rb = 4*q + i;
      int d = w*32 + t*16 + col;
      hn_bf[((size_t)p*BATCH + b0 + rb)*DIM + d] = f2bf(hreg[t][i]);
    }
  }
}

// ---------------- kernel 6: scores = sum_p tcw[t,p] * (hn_p @ emb.T) ----------------
__global__ __launch_bounds__(256) void k_score(const unsigned short* __restrict__ emb_bf,
        const unsigned short* __restrict__ hn_bf, const float* __restrict__ tcw,
        float* __restrict__ out){
  int w = threadIdx.x >> 6, lane = threadIdx.x & 63;
  int col = lane & 15, q = lane >> 4, kq = q*8;
  int trow = blockIdx.x*64 + w*16 + col;
  float4_ z4 = {0.f,0.f,0.f,0.f};
  float4_ acc[3][8];
  #pragma unroll
  for (int p=0;p<3;p++){
    #pragma unroll
    for (int m=0;m<8;m++) acc[p][m] = z4;
  }
  const unsigned short* E = emb_bf + (size_t)trow*DIM + kq;
  #pragma unroll
  for (int kf=0; kf<8; kf++){
    short8 bb = *(const short8*)(E + kf*32);
    #pragma unroll
    for (int p=0;p<3;p++){
      #pragma unroll
      for (int m=0;m<8;m++){
        short8 a = *(const short8*)(hn_bf + ((size_t)p*BATCH + m*16 + col)*DIM + kf*32 + kq);
        acc[p][m] = __builtin_amdgcn_mfma_f32_16x16x32_bf16(a, bb, acc[p][m], 0, 0, 0);
      }
    }
  }
  if (trow < NITEMS){
    float w0 = tcw[trow*3+0], w1 = tcw[trow*3+1], w2 = tcw[trow*3+2];
    #pragma unroll
    for (int m=0;m<8;m++){
      #pragma unroll
      for (int i=0;i<4;i++){
        int b = m*16 + 4*q + i;
        out[(size_t)b*NITEMS + trow] = w0*acc[0][m][i] + w1*acc[1][m][i] + w2*acc[2][m][i];
      }
    }
  }
}

extern "C" void kernel_launch(void* const* d_in, const int* in_sizes, int n_in,
                              void* d_out, int out_size, void* d_ws, size_t ws_size,
                              hipStream_t stream) {
  const int*   seq  = (const int*)d_in[0];
  const float* emb  = (const float*)d_in[1];
  const float* embp = (const float*)d_in[2];
  const float* wih  = (const float*)d_in[3];
  const float* whh  = (const float*)d_in[4];
  const float* bih  = (const float*)d_in[5];
  const float* bhh  = (const float*)d_in[6];
  float* out = (float*)d_out;

  char* ws = (char*)d_ws;
  size_t off = 0;
  auto alloc = [&](size_t bytes) -> void* {
    void* r = ws + off; off += (bytes + 255) & ~(size_t)255; return r;
  };
  unsigned short* emb_bf = (unsigned short*)alloc((size_t)NPAD*DIM*2);
  unsigned short* x_bf   = (unsigned short*)alloc((size_t)NSEQ*DIM*2);
  unsigned short* wih_bf = (unsigned short*)alloc((size_t)3*GDIM*DIM*2);
  unsigned short* whh_bf = (unsigned short*)alloc((size_t)3*GDIM*DIM*2);
  unsigned short* gi2    = (unsigned short*)alloc((size_t)3*NSEQ*GDIM*2);
  float* tcw = (float*)alloc((size_t)NITEMS*3*4);
  float* cfb = (float*)alloc((size_t)3*NSEQ*4);
  unsigned short* hn_bf = (unsigned short*)alloc((size_t)3*BATCH*DIM*2);

  k_conv_w<<<1152, 256, 0, stream>>>(wih, whh, wih_bf, whh_bf, 3*GDIM*DIM/4);
  k_emb<<<(NITEMS+3)/4, 256, 0, stream>>>(emb, embp, emb_bf, tcw);
  k_gather<<<NSEQ/4, 256, 0, stream>>>(seq, emb, embp, x_bf, cfb);
  dim3 gg(GDIM/64, NSEQ/64, 3);
  k_gi<<<gg, 256, 0, stream>>>(x_bf, wih_bf, bih, bhh, gi2);

  (void)hipFuncSetAttribute((const void*)k_rnn,
        hipFuncAttributeMaxDynamicSharedMemorySize, 150656);
  k_rnn<<<24, 512, 150656, stream>>>(whh_bf, gi2, bhh, cfb, hn_bf);

  k_score<<<NPAD/64, 256, 0, stream>>>(emb_bf, hn_bf, tcw, out);
}